// Round 4
// baseline (3325.354 us; speedup 1.0000x reference)
//
#include <hip/hip_runtime.h>
#include <math.h>

#define N_TOK 1024
#define DV    400
#define G4    1600
#define DWD   300
#define DPD   100
#define HID   512
#define FD    128
#define GWG   50      // workgroups per LSTM direction
#define EPW   8       // hidden elements per WG (DV / GWG)

__device__ __forceinline__ float sigmoidf_(float x){ return 1.0f/(1.0f+__expf(-x)); }

#define LDA(p) __hip_atomic_load((p), __ATOMIC_RELAXED, __HIP_MEMORY_SCOPE_AGENT)

// ---------------- embedding gather: x[t] = [word_emb[wid], pos_emb[pid]] ----------------
__global__ void k_gather(const int* __restrict__ wid, const int* __restrict__ pid,
                         const float* __restrict__ wemb, const float* __restrict__ pemb,
                         float* __restrict__ x)
{
    int t = blockIdx.x;
    int w = wid[t], p = pid[t];
    for (int k = threadIdx.x; k < DV; k += blockDim.x){
        float v = (k < DWD) ? wemb[(long)w*DWD + k] : pemb[p*DPD + (k - DWD)];
        x[t*DV + k] = v;
    }
}

// ---------------- tiny transpose (U_1 -> U_1^T) ----------------
__global__ void k_transpose(const float* __restrict__ U, float* __restrict__ Ut, int n)
{
    int j = blockIdx.y*16 + threadIdx.y;
    int k = blockIdx.x*16 + threadIdx.x;
    if (j < n && k < n) Ut[j*n + k] = U[k*n + j];
}

// ---------------- fp32 NT GEMM: C[M][Nn] = A[M][K] * B[Nn][K]^T (+biases, relu) -------
__global__ __launch_bounds__(256) void k_gemm_nt(
    const float* __restrict__ A, const float* __restrict__ B,
    const float* __restrict__ bias1, const float* __restrict__ bias2,
    const float* __restrict__ rowbias, float* __restrict__ C,
    int M, int Nn, int K, int revA, int relu)
{
    const int BM = 64, BN = 64, BK = 16;
    __shared__ float As[BK][BM];
    __shared__ float Bs[BK][BN];
    int tid = threadIdx.x;
    int tx = tid & 15, ty = tid >> 4;
    int m0 = blockIdx.y*BM, n0 = blockIdx.x*BN;
    int lrow = tid >> 2;          // 0..63
    int lk   = (tid & 3) * 4;     // 0,4,8,12
    float acc[4][4] = {{0.f}};

    for (int k0 = 0; k0 < K; k0 += BK){
        int am = m0 + lrow; if (revA) am = M - 1 - am;
        const float4 av = *(const float4*)&A[(long)am*K + k0 + lk];
        const float4 bv = *(const float4*)&B[(long)(n0 + lrow)*K + k0 + lk];
        As[lk+0][lrow] = av.x; As[lk+1][lrow] = av.y; As[lk+2][lrow] = av.z; As[lk+3][lrow] = av.w;
        Bs[lk+0][lrow] = bv.x; Bs[lk+1][lrow] = bv.y; Bs[lk+2][lrow] = bv.z; Bs[lk+3][lrow] = bv.w;
        __syncthreads();
        #pragma unroll
        for (int kk = 0; kk < BK; ++kk){
            const float4 a = *(const float4*)&As[kk][ty*4];
            const float4 b = *(const float4*)&Bs[kk][tx*4];
            const float ar[4] = {a.x, a.y, a.z, a.w};
            const float br[4] = {b.x, b.y, b.z, b.w};
            #pragma unroll
            for (int i = 0; i < 4; ++i)
                #pragma unroll
                for (int j = 0; j < 4; ++j)
                    acc[i][j] += ar[i]*br[j];
        }
        __syncthreads();
    }

    #pragma unroll
    for (int i = 0; i < 4; ++i){
        int m = m0 + ty*4 + i;
        float rb = rowbias ? rowbias[m] : 0.0f;
        #pragma unroll
        for (int j = 0; j < 4; ++j){
            int n = n0 + tx*4 + j;
            float v = acc[i][j] + rb;
            if (bias1) v += bias1[n];
            if (bias2) v += bias2[n];
            if (relu)  v = fmaxf(v, 0.0f);
            C[(long)m*Nn + n] = v;
        }
    }
}

// ---------------- persistent BiLSTM — pipelined-poll mailbox, W in registers ----------
// Mailbox: per-(dir,t,element) 64-bit (tag|value) slots, one relaxed agent-scope 8B
// store per element (indivisible => tag!=0 implies value valid). Consumers run a
// depth-3 software-pipelined poll ring per slot (sampling period ~RT/3), primed BEFORE
// the dot so flight time overlaps compute. Whh lives in 50 VGPRs/thread for the whole
// kernel; h is double-buffered in LDS so each step needs exactly ONE barrier.
__global__ __launch_bounds__(256, 1) void k_lstm(
    const float* __restrict__ Whh_f, const float* __restrict__ Whh_b,
    const float* __restrict__ Xf, const float* __restrict__ Xb,
    const float* __restrict__ h0, const float* __restrict__ c0,
    float* __restrict__ hf, float* __restrict__ hb,
    unsigned long long* __restrict__ mbox)
{
    __shared__ float hA[DV];
    __shared__ float hB[DV];

    int tid = threadIdx.x;
    int dir = blockIdx.x / GWG;
    int g   = blockIdx.x % GWG;
    int j0  = g * EPW;
    const float* Whh = dir ? Whh_b : Whh_f;
    const float* XX  = dir ? Xb    : Xf;
    float*       hout= dir ? hb    : hf;
    unsigned long long* mb = mbox + (size_t)dir * N_TOK * DV;

    int w    = tid >> 6;        // wave 0..3
    int lane = tid & 63;
    int q    = lane >> 4;       // gate 0..3 (i,f,g,o)
    int eo   = (lane >> 3) & 1; // element parity within wave
    int l    = lane & 7;        // lane within row octet
    int e    = 2*w + eo;        // element 0..7 owned by this octet's wave
    int grow = q*DV + j0 + e;   // global gate row index
    bool owner = (q == 0) && (l == 0);
    float c_reg = owner ? c0[dir*DV + j0 + e] : 0.0f;

    // Whh row slice -> registers for the whole kernel (thread covers floats 2l+16i)
    float2 wreg[25];
    {
        const float* wrow = Whh + (size_t)grow * DV;
        #pragma unroll
        for (int i = 0; i < 25; ++i)
            wreg[i] = *(const float2*)&wrow[2*l + 16*i];
    }

    for (int idx = tid; idx < DV; idx += 256) hA[idx] = h0[dir*DV + idx];

    // consumer slot assignment: thread tid polls slot tid (and 256+tid if tid<144)
    int s0 = tid;
    int s1 = 256 + tid;
    bool own0 = (s0 >= j0) && (s0 < j0 + EPW);
    bool own1 = (tid < 144) && (s1 >= j0) && (s1 < j0 + EPW);
    bool skip1 = own1 || (tid >= 144);
    __syncthreads();

    // X prefetch for t=0
    float xv_n = 0.0f;
    if (l == 0) xv_n = XX[grow];

    bool dead = false;
    for (int t = 0; t < N_TOK; ++t){
        const unsigned long long* mrow = &mb[(size_t)t*DV];
        const unsigned long long* p0 = &mrow[s0];
        const unsigned long long* p1 = (tid < 144) ? &mrow[s1] : p0;

        // prime the poll rings BEFORE computing (flight overlaps the dot)
        unsigned long long q0a = LDA(p0), q1a = LDA(p1);
        unsigned long long q0b = LDA(p0), q1b = LDA(p1);
        unsigned long long q0c = LDA(p0), q1c = LDA(p1);

        float xv = xv_n;
        // X prefetch for t+1 (lands during this step's poll)
        if (l == 0){
            int tn = (t + 1 < N_TOK) ? (t + 1) : t;
            xv_n = XX[(size_t)tn*G4 + grow];
        }

        // matvec: row grow dot h_cur (8 lanes/row, W in regs, h from LDS)
        const float2* hc2 = (const float2*)((t & 1) ? hB : hA);
        float sum = 0.0f;
        #pragma unroll
        for (int i = 0; i < 25; ++i){
            float2 hv = hc2[l + 8*i];
            sum += wreg[i].x*hv.x + wreg[i].y*hv.y;
        }
        sum += __shfl_xor(sum, 1, 8);
        sum += __shfl_xor(sum, 2, 8);
        sum += __shfl_xor(sum, 4, 8);
        if (l == 0) sum += xv;

        // gather the 4 gate totals for my wave's element e
        float gi = __shfl(sum, eo*8 + 0,  64);
        float gf = __shfl(sum, eo*8 + 16, 64);
        float gg = __shfl(sum, eo*8 + 32, 64);
        float go = __shfl(sum, eo*8 + 48, 64);

        float* hn = (t & 1) ? hA : hB;   // next-h buffer (cur is untouched)

        if (owner){
            float iv = sigmoidf_(gi);
            float fv = sigmoidf_(gf);
            float gv = tanhf(gg);
            float ov = sigmoidf_(go);
            c_reg = fv*c_reg + iv*gv;
            float h_new = ov * tanhf(c_reg);
            unsigned long long pk = (1ull << 32) | (unsigned long long)__float_as_uint(h_new);
            __hip_atomic_store(&mb[(size_t)t*DV + j0 + e], pk,
                               __ATOMIC_RELAXED, __HIP_MEMORY_SCOPE_AGENT);
            hout[(long)t*DV + j0 + e] = h_new;   // plain store for post-LSTM kernels
            hn[j0 + e] = h_new;                  // own elements bypass mailbox
        }

        // depth-3 pipelined poll (named regs only; oldest-first check, reissue on miss)
        if (!dead){
            bool g0 = own0, g1 = skip1;
            int guard = 0;
            while (!(g0 && g1)){
                if (!g0){
                    if (q0a >> 32){ hn[s0] = __uint_as_float((unsigned)q0a); g0 = true; }
                    else { q0a = q0b; q0b = q0c; q0c = LDA(p0); }
                }
                if (!g1){
                    if (q1a >> 32){ hn[s1] = __uint_as_float((unsigned)q1a); g1 = true; }
                    else { q1a = q1b; q1b = q1c; q1c = LDA(p1); }
                }
                if (++guard > (1 << 18)) { dead = true; break; }  // no-hang safety
            }
        }
        __syncthreads();   // single barrier per step: hn complete, hc free for reuse
    }
}

// ---------------- sr = sigmoid(concat(hf[t], hb[N-1-t])) ----------------
__global__ void k_sr(const float* __restrict__ hf, const float* __restrict__ hb,
                     float* __restrict__ sr)
{
    int t = blockIdx.x;
    for (int c = threadIdx.x; c < 2*DV; c += blockDim.x){
        float v = (c < DV) ? hf[t*DV + c] : hb[(N_TOK-1-t)*DV + (c - DV)];
        sr[t*2*DV + c] = 1.0f/(1.0f+__expf(-v));
    }
}

// ---------------- bvec[i] = dot(Hh[i], u2) ----------------
__global__ void k_bvec(const float* __restrict__ Hh, const float* __restrict__ u2,
                       float* __restrict__ bvec)
{
    int i = blockIdx.x;
    int lane = threadIdx.x;
    float v = Hh[i*FD + lane]*u2[lane] + Hh[i*FD + 64 + lane]*u2[64 + lane];
    v += __shfl_xor(v, 1, 64);
    v += __shfl_xor(v, 2, 64);
    v += __shfl_xor(v, 4, 64);
    v += __shfl_xor(v, 8, 64);
    v += __shfl_xor(v, 16, 64);
    v += __shfl_xor(v, 32, 64);
    if (lane == 0) bvec[i] = v;
}

extern "C" void kernel_launch(void* const* d_in, const int* in_sizes, int n_in,
                              void* d_out, int out_size, void* d_ws, size_t ws_size,
                              hipStream_t stream)
{
    const int*   word_ids = (const int*)  d_in[0];
    const int*   pos_ids  = (const int*)  d_in[1];
    const float* h0    = (const float*)d_in[2];
    const float* c0    = (const float*)d_in[3];
    const float* wemb  = (const float*)d_in[4];
    const float* pemb  = (const float*)d_in[5];
    const float* Wih_f = (const float*)d_in[6];
    const float* Whh_f = (const float*)d_in[7];
    const float* bih_f = (const float*)d_in[8];
    const float* bhh_f = (const float*)d_in[9];
    const float* Wih_b = (const float*)d_in[10];
    const float* Whh_b = (const float*)d_in[11];
    const float* bih_b = (const float*)d_in[12];
    const float* bhh_b = (const float*)d_in[13];
    const float* Wh1   = (const float*)d_in[14];
    const float* bh1   = (const float*)d_in[15];
    const float* Wh2   = (const float*)d_in[16];
    const float* bh2   = (const float*)d_in[17];
    const float* Wd1   = (const float*)d_in[18];
    const float* bd1   = (const float*)d_in[19];
    const float* Wd2   = (const float*)d_in[20];
    const float* bd2   = (const float*)d_in[21];
    const float* U1    = (const float*)d_in[22];
    const float* u2    = (const float*)d_in[23];
    float* out = (float*)d_out;

    // workspace layout (floats)
    float* ws  = (float*)d_ws;
    float* x    = ws;                 // 1024*400
    float* Xf   = ws + 409600;        // 1024*1600
    float* Xb   = ws + 2048000;       // 1024*1600
    float* hf   = ws + 3686400;       // 1024*400
    float* hb   = ws + 4096000;       // 1024*400
    float* sr   = ws + 4505600;       // 1024*800   (aliased by mbox during LSTM)
    float* T1h  = ws + 5324800;       // 1024*512   (aliased by mbox during LSTM)
    float* T1d  = ws + 5849088;       // 1024*512   (partially aliased by mbox)
    float* Hh   = ws + 6373376;       // 1024*128
    float* Hd   = ws + 6504448;       // 1024*128
    float* G1   = ws + 6635520;       // 1024*128
    float* Ut   = ws + 6766592;       // 128*128
    float* bvec = ws + 6782976;       // 1024
    // mailbox: 2*1024*400 slots x 8B = 6.55 MB in [4505600, 6144000) floats;
    // sr/T1h/T1d are written strictly after k_lstm completes.
    unsigned long long* mbox = (unsigned long long*)(ws + 4505600);

    hipMemsetAsync(mbox, 0, (size_t)2*N_TOK*DV*sizeof(unsigned long long), stream);

    k_gather<<<N_TOK, 128, 0, stream>>>(word_ids, pos_ids, wemb, pemb, x);
    k_transpose<<<dim3(8,8), dim3(16,16), 0, stream>>>(U1, Ut, FD);

    dim3 blk(256);
    // input projections (recurrence-free): Xf/Xb = x((rev)) @ Wih^T + bih + bhh
    k_gemm_nt<<<dim3(G4/64, N_TOK/64), blk, 0, stream>>>(x, Wih_f, bih_f, bhh_f, nullptr, Xf,
                                                         N_TOK, G4, DV, 0, 0);
    k_gemm_nt<<<dim3(G4/64, N_TOK/64), blk, 0, stream>>>(x, Wih_b, bih_b, bhh_b, nullptr, Xb,
                                                         N_TOK, G4, DV, 1, 0);
    // sequential recurrence
    k_lstm<<<2*GWG, 256, 0, stream>>>(Whh_f, Whh_b, Xf, Xb, h0, c0, hf, hb, mbox);

    k_sr<<<N_TOK, 256, 0, stream>>>(hf, hb, sr);

    // MLPs
    k_gemm_nt<<<dim3(HID/64, N_TOK/64), blk, 0, stream>>>(sr, Wh1, bh1, nullptr, nullptr, T1h,
                                                          N_TOK, HID, 2*DV, 0, 1);
    k_gemm_nt<<<dim3(HID/64, N_TOK/64), blk, 0, stream>>>(sr, Wd1, bd1, nullptr, nullptr, T1d,
                                                          N_TOK, HID, 2*DV, 0, 1);
    k_gemm_nt<<<dim3(FD/64,  N_TOK/64), blk, 0, stream>>>(T1h, Wh2, bh2, nullptr, nullptr, Hh,
                                                          N_TOK, FD, HID, 0, 0);
    k_gemm_nt<<<dim3(FD/64,  N_TOK/64), blk, 0, stream>>>(T1d, Wd2, bd2, nullptr, nullptr, Hd,
                                                          N_TOK, FD, HID, 0, 0);
    // biaffine
    k_bvec<<<N_TOK, 64, 0, stream>>>(Hh, u2, bvec);
    k_gemm_nt<<<dim3(FD/64,  N_TOK/64), blk, 0, stream>>>(Hh, Ut, nullptr, nullptr, nullptr, G1,
                                                          N_TOK, FD, FD, 0, 0);
    k_gemm_nt<<<dim3(N_TOK/64, N_TOK/64), blk, 0, stream>>>(G1, Hd, nullptr, nullptr, bvec, out,
                                                            N_TOK, N_TOK, FD, 0, 0);
}

// Round 6
// 3152.046 us; speedup vs baseline: 1.0550x; 1.0550x over previous
//
#include <hip/hip_runtime.h>
#include <math.h>

#define N_TOK 1024
#define DV    400
#define G4    1600
#define DWD   300
#define DPD   100
#define HID   512
#define FD    128
#define GWG   25     // workgroups per LSTM direction
#define EPW   16     // hidden elements per WG (DV / GWG)

__device__ __forceinline__ float sigmoidf_(float x){ return 1.0f/(1.0f+__expf(-x)); }
// overflow-safe fast tanh: exp of a NEGATIVE argument only
__device__ __forceinline__ float tanh_safe(float x){
    float t = __expf(-2.0f*fabsf(x));
    float r = (1.0f - t)/(1.0f + t);
    return copysignf(r, x);
}

#define LDA(p) __hip_atomic_load((p), __ATOMIC_RELAXED, __HIP_MEMORY_SCOPE_AGENT)

// ---------------- embedding gather: x[t] = [word_emb[wid], pos_emb[pid]] ----------------
__global__ void k_gather(const int* __restrict__ wid, const int* __restrict__ pid,
                         const float* __restrict__ wemb, const float* __restrict__ pemb,
                         float* __restrict__ x)
{
    int t = blockIdx.x;
    int w = wid[t], p = pid[t];
    for (int k = threadIdx.x; k < DV; k += blockDim.x){
        float v = (k < DWD) ? wemb[(long)w*DWD + k] : pemb[p*DPD + (k - DWD)];
        x[t*DV + k] = v;
    }
}

// ---------------- tiny transpose (U_1 -> U_1^T) ----------------
__global__ void k_transpose(const float* __restrict__ U, float* __restrict__ Ut, int n)
{
    int j = blockIdx.y*16 + threadIdx.y;
    int k = blockIdx.x*16 + threadIdx.x;
    if (j < n && k < n) Ut[j*n + k] = U[k*n + j];
}

// ---------------- fp32 NT GEMM: C[M][Nn] = A[M][K] * B[Nn][K]^T (+biases, relu) -------
__global__ __launch_bounds__(256) void k_gemm_nt(
    const float* __restrict__ A, const float* __restrict__ B,
    const float* __restrict__ bias1, const float* __restrict__ bias2,
    const float* __restrict__ rowbias, float* __restrict__ C,
    int M, int Nn, int K, int revA, int relu)
{
    const int BM = 64, BN = 64, BK = 16;
    __shared__ float As[BK][BM];
    __shared__ float Bs[BK][BN];
    int tid = threadIdx.x;
    int tx = tid & 15, ty = tid >> 4;
    int m0 = blockIdx.y*BM, n0 = blockIdx.x*BN;
    int lrow = tid >> 2;          // 0..63
    int lk   = (tid & 3) * 4;     // 0,4,8,12
    float acc[4][4] = {{0.f}};

    for (int k0 = 0; k0 < K; k0 += BK){
        int am = m0 + lrow; if (revA) am = M - 1 - am;
        const float4 av = *(const float4*)&A[(long)am*K + k0 + lk];
        const float4 bv = *(const float4*)&B[(long)(n0 + lrow)*K + k0 + lk];
        As[lk+0][lrow] = av.x; As[lk+1][lrow] = av.y; As[lk+2][lrow] = av.z; As[lk+3][lrow] = av.w;
        Bs[lk+0][lrow] = bv.x; Bs[lk+1][lrow] = bv.y; Bs[lk+2][lrow] = bv.z; Bs[lk+3][lrow] = bv.w;
        __syncthreads();
        #pragma unroll
        for (int kk = 0; kk < BK; ++kk){
            const float4 a = *(const float4*)&As[kk][ty*4];
            const float4 b = *(const float4*)&Bs[kk][tx*4];
            const float ar[4] = {a.x, a.y, a.z, a.w};
            const float br[4] = {b.x, b.y, b.z, b.w};
            #pragma unroll
            for (int i = 0; i < 4; ++i)
                #pragma unroll
                for (int j = 0; j < 4; ++j)
                    acc[i][j] += ar[i]*br[j];
        }
        __syncthreads();
    }

    #pragma unroll
    for (int i = 0; i < 4; ++i){
        int m = m0 + ty*4 + i;
        float rb = rowbias ? rowbias[m] : 0.0f;
        #pragma unroll
        for (int j = 0; j < 4; ++j){
            int n = n0 + tx*4 + j;
            float v = acc[i][j] + rb;
            if (bias1) v += bias1[n];
            if (bias2) v += bias2[n];
            if (relu)  v = fmaxf(v, 0.0f);
            C[(long)m*Nn + n] = v;
        }
    }
}

// ---------------- persistent BiLSTM — agent-scope mailbox (r3 semantics, PROVEN) ------
// + spill-free weights: 25 NAMED float4 VGPRs per thread (macro-expanded, no array).
// Layout: 50 WGs total (25/dir), each owns EPW=16 hidden elements = 64 gate rows;
// each row computed by 4 threads (100 floats each), reduced via shfl_xor(width 4).
// Exchange: one relaxed agent-scope 8B atomic store per element (tag<<32 | h bits);
// 8B atomicity => tag!=0 implies value valid. Consumers prime depth-3 poll rings
// BEFORE the dot so load flight overlaps compute.
#define REP25(M) M(0) M(1) M(2) M(3) M(4) M(5) M(6) M(7) M(8) M(9) M(10) M(11) \
                 M(12) M(13) M(14) M(15) M(16) M(17) M(18) M(19) M(20) M(21) M(22) M(23) M(24)
#define DECLW(i) float4 w##i;
#define LOADW(i) w##i = *(const float4*)&wrow[(i)*4];
#define DOTW(i)  { float4 hv = h4[i]; \
                   sum = fmaf(w##i.x, hv.x, sum); sum = fmaf(w##i.y, hv.y, sum); \
                   sum = fmaf(w##i.z, hv.z, sum); sum = fmaf(w##i.w, hv.w, sum); }

__global__ __launch_bounds__(256) void k_lstm(
    const float* __restrict__ Whh_f, const float* __restrict__ Whh_b,
    const float* __restrict__ Xf, const float* __restrict__ Xb,
    const float* __restrict__ h0, const float* __restrict__ c0,
    float* __restrict__ hf, float* __restrict__ hb,
    unsigned long long* __restrict__ mbox)
{
    __shared__ __align__(16) float hA[DV];
    __shared__ __align__(16) float hB[DV];
    __shared__ __align__(16) float gs[EPW*4];   // gs[e*4+q] gate partials

    int tid = threadIdx.x;
    int dir = blockIdx.x / GWG;
    int g   = blockIdx.x % GWG;
    int j0  = g * EPW;
    const float* XX  = dir ? Xb : Xf;
    float*       hout= dir ? hb : hf;
    unsigned long long* mb = mbox + (size_t)dir * N_TOK * DV;

    // dot-role: row r = q*16+e (64 rows), 4 threads/row each covering 100 k-floats
    int r    = tid >> 2;            // 0..63
    int sub  = tid & 3;
    int q    = r >> 4;              // gate 0..3 (i,f,g,o)
    int e    = r & 15;              // element within WG slice
    int grow = q*DV + j0 + e;       // global gate row

    // weights -> 25 named float4 VGPRs (no array => no scratch demotion)
    const float* wrow = (dir ? Whh_b : Whh_f) + (size_t)grow*DV + sub*100;
    REP25(DECLW)
    REP25(LOADW)

    // producer-role: threads 0..15 own element e=tid (gate combine + c,h state)
    float c_reg = (tid < EPW) ? c0[dir*DV + j0 + tid] : 0.0f;

    for (int idx = tid; idx < DV; idx += 256) hA[idx] = h0[dir*DV + idx];

    // poll-role: thread polls slot tid (and 256+tid if tid<144)
    int s0 = tid;
    int s1 = 256 + tid;
    bool own0  = (s0 >= j0) && (s0 < j0 + EPW);
    bool skip1 = (tid >= DV - 256) || ((s1 >= j0) && (s1 < j0 + EPW));
    __syncthreads();

    float xv_n = (sub == 0) ? XX[grow] : 0.0f;   // X prefetch for t=0

    bool dead = false;
    for (int t = 0; t < N_TOK; ++t){
        const float* hc = (t & 1) ? hB : hA;
        float*       hn = (t & 1) ? hA : hB;

        const unsigned long long* p0 = mb + (size_t)t*DV + s0;
        const unsigned long long* p1 = mb + (size_t)t*DV + ((tid < DV-256) ? s1 : s0);

        // prime the poll rings BEFORE computing (flight overlaps the dot)
        unsigned long long q0a = LDA(p0), q1a = LDA(p1);
        unsigned long long q0b = LDA(p0), q1b = LDA(p1);
        unsigned long long q0c = LDA(p0), q1c = LDA(p1);

        float xv = xv_n;
        // X prefetch for t+1 (lands during this step's poll)
        if (sub == 0){
            int tn = (t + 1 < N_TOK) ? (t + 1) : t;
            xv_n = XX[(size_t)tn*G4 + grow];
        }

        // matvec: 100 MACs/thread, W in regs, h broadcast from LDS
        const float4* h4 = (const float4*)hc + sub*25;
        float sum = 0.0f;
        REP25(DOTW)
        sum += __shfl_xor(sum, 1, 4);
        sum += __shfl_xor(sum, 2, 4);
        if (sub == 0) gs[e*4 + q] = sum + xv;
        __syncthreads();

        // producers: combine gates, update c, publish h (one 8B agent-scope store)
        if (tid < EPW){
            float4 gv = *(const float4*)&gs[tid*4];   // (i,f,g,o) pre-activations
            float iv = sigmoidf_(gv.x);
            float fv = sigmoidf_(gv.y);
            float gg = tanh_safe(gv.z);
            float ov = sigmoidf_(gv.w);
            c_reg = fv*c_reg + iv*gg;
            float hvv = ov * tanh_safe(c_reg);
            unsigned long long pk = (1ull << 32) | (unsigned long long)__float_as_uint(hvv);
            __hip_atomic_store(mb + (size_t)t*DV + j0 + tid, pk,
                               __ATOMIC_RELAXED, __HIP_MEMORY_SCOPE_AGENT);
            hout[(long)t*DV + j0 + tid] = hvv;   // plain store for post-LSTM kernels
            hn[j0 + tid] = hvv;                  // own elements bypass mailbox
        }

        // depth-3 pipelined poll (named regs; oldest-first check, reissue on miss)
        if (!dead){
            bool g0 = own0, g1 = skip1;
            int guard = 0;
            while (!(g0 && g1)){
                if (!g0){
                    if (q0a >> 32){ hn[s0] = __uint_as_float((unsigned)q0a); g0 = true; }
                    else { q0a = q0b; q0b = q0c; q0c = LDA(p0); }
                }
                if (!g1){
                    if (q1a >> 32){ hn[s1] = __uint_as_float((unsigned)q1a); g1 = true; }
                    else { q1a = q1b; q1b = q1c; q1c = LDA(p1); }
                }
                if (++guard > (1 << 18)) { dead = true; break; }  // no-hang safety
            }
        }
        __syncthreads();   // hn complete; hc free for next step's writers
    }
}

// ---------------- sr = sigmoid(concat(hf[t], hb[N-1-t])) ----------------
__global__ void k_sr(const float* __restrict__ hf, const float* __restrict__ hb,
                     float* __restrict__ sr)
{
    int t = blockIdx.x;
    for (int c = threadIdx.x; c < 2*DV; c += blockDim.x){
        float v = (c < DV) ? hf[t*DV + c] : hb[(N_TOK-1-t)*DV + (c - DV)];
        sr[t*2*DV + c] = 1.0f/(1.0f+__expf(-v));
    }
}

// ---------------- bvec[i] = dot(Hh[i], u2) ----------------
__global__ void k_bvec(const float* __restrict__ Hh, const float* __restrict__ u2,
                       float* __restrict__ bvec)
{
    int i = blockIdx.x;
    int lane = threadIdx.x;
    float v = Hh[i*FD + lane]*u2[lane] + Hh[i*FD + 64 + lane]*u2[64 + lane];
    v += __shfl_xor(v, 1, 64);
    v += __shfl_xor(v, 2, 64);
    v += __shfl_xor(v, 4, 64);
    v += __shfl_xor(v, 8, 64);
    v += __shfl_xor(v, 16, 64);
    v += __shfl_xor(v, 32, 64);
    if (lane == 0) bvec[i] = v;
}

extern "C" void kernel_launch(void* const* d_in, const int* in_sizes, int n_in,
                              void* d_out, int out_size, void* d_ws, size_t ws_size,
                              hipStream_t stream)
{
    const int*   word_ids = (const int*)  d_in[0];
    const int*   pos_ids  = (const int*)  d_in[1];
    const float* h0    = (const float*)d_in[2];
    const float* c0    = (const float*)d_in[3];
    const float* wemb  = (const float*)d_in[4];
    const float* pemb  = (const float*)d_in[5];
    const float* Wih_f = (const float*)d_in[6];
    const float* Whh_f = (const float*)d_in[7];
    const float* bih_f = (const float*)d_in[8];
    const float* bhh_f = (const float*)d_in[9];
    const float* Wih_b = (const float*)d_in[10];
    const float* Whh_b = (const float*)d_in[11];
    const float* bih_b = (const float*)d_in[12];
    const float* bhh_b = (const float*)d_in[13];
    const float* Wh1   = (const float*)d_in[14];
    const float* bh1   = (const float*)d_in[15];
    const float* Wh2   = (const float*)d_in[16];
    const float* bh2   = (const float*)d_in[17];
    const float* Wd1   = (const float*)d_in[18];
    const float* bd1   = (const float*)d_in[19];
    const float* Wd2   = (const float*)d_in[20];
    const float* bd2   = (const float*)d_in[21];
    const float* U1    = (const float*)d_in[22];
    const float* u2    = (const float*)d_in[23];
    float* out = (float*)d_out;

    // workspace layout (floats)
    float* ws  = (float*)d_ws;
    float* x    = ws;                 // 1024*400
    float* Xf   = ws + 409600;        // 1024*1600
    float* Xb   = ws + 2048000;       // 1024*1600
    float* hf   = ws + 3686400;       // 1024*400
    float* hb   = ws + 4096000;       // 1024*400
    float* sr   = ws + 4505600;       // 1024*800   (aliased by mbox during LSTM)
    float* T1h  = ws + 5324800;       // 1024*512   (aliased by mbox during LSTM)
    float* T1d  = ws + 5849088;       // 1024*512   (partially aliased by mbox)
    float* Hh   = ws + 6373376;       // 1024*128
    float* Hd   = ws + 6504448;       // 1024*128
    float* G1   = ws + 6635520;       // 1024*128
    float* Ut   = ws + 6766592;       // 128*128
    float* bvec = ws + 6782976;       // 1024
    // mailbox: 2*1024*400 slots x 8B = 6.55 MB in floats [4505600, 6144000);
    // sr/T1h/T1d are written strictly after k_lstm completes.
    unsigned long long* mbox = (unsigned long long*)(ws + 4505600);

    hipMemsetAsync(mbox, 0, (size_t)2*N_TOK*DV*sizeof(unsigned long long), stream);

    k_gather<<<N_TOK, 128, 0, stream>>>(word_ids, pos_ids, wemb, pemb, x);
    k_transpose<<<dim3(8,8), dim3(16,16), 0, stream>>>(U1, Ut, FD);

    dim3 blk(256);
    // input projections (recurrence-free): Xf/Xb = x((rev)) @ Wih^T + bih + bhh
    k_gemm_nt<<<dim3(G4/64, N_TOK/64), blk, 0, stream>>>(x, Wih_f, bih_f, bhh_f, nullptr, Xf,
                                                         N_TOK, G4, DV, 0, 0);
    k_gemm_nt<<<dim3(G4/64, N_TOK/64), blk, 0, stream>>>(x, Wih_b, bih_b, bhh_b, nullptr, Xb,
                                                         N_TOK, G4, DV, 1, 0);
    // sequential recurrence: 50 WGs, one per CU
    k_lstm<<<2*GWG, 256, 0, stream>>>(Whh_f, Whh_b, Xf, Xb, h0, c0, hf, hb, mbox);

    k_sr<<<N_TOK, 256, 0, stream>>>(hf, hb, sr);

    // MLPs
    k_gemm_nt<<<dim3(HID/64, N_TOK/64), blk, 0, stream>>>(sr, Wh1, bh1, nullptr, nullptr, T1h,
                                                          N_TOK, HID, 2*DV, 0, 1);
    k_gemm_nt<<<dim3(HID/64, N_TOK/64), blk, 0, stream>>>(sr, Wd1, bd1, nullptr, nullptr, T1d,
                                                          N_TOK, HID, 2*DV, 0, 1);
    k_gemm_nt<<<dim3(FD/64,  N_TOK/64), blk, 0, stream>>>(T1h, Wh2, bh2, nullptr, nullptr, Hh,
                                                          N_TOK, FD, HID, 0, 0);
    k_gemm_nt<<<dim3(FD/64,  N_TOK/64), blk, 0, stream>>>(T1d, Wd2, bd2, nullptr, nullptr, Hd,
                                                          N_TOK, FD, HID, 0, 0);
    // biaffine
    k_bvec<<<N_TOK, 64, 0, stream>>>(Hh, u2, bvec);
    k_gemm_nt<<<dim3(FD/64,  N_TOK/64), blk, 0, stream>>>(Hh, Ut, nullptr, nullptr, nullptr, G1,
                                                          N_TOK, FD, FD, 0, 0);
    k_gemm_nt<<<dim3(N_TOK/64, N_TOK/64), blk, 0, stream>>>(G1, Hd, nullptr, nullptr, bvec, out,
                                                            N_TOK, N_TOK, FD, 0, 0);
}